// Round 4
// baseline (887.789 us; speedup 1.0000x reference)
//
#include <hip/hip_runtime.h>

#define N_NODES 100000
#define D_IN 64
#define HID 128
#define N_EDGES 1600000
#define N_LBL 500000

// ---------------- degree histogram (int) ----------------
__global__ __launch_bounds__(256) void k_deg(const int* __restrict__ dst,
                                             int* __restrict__ deg) {
  int e = blockIdx.x * 256 + threadIdx.x;
  if (e < N_EDGES) atomicAdd(&deg[dst[e]], 1);
}

__global__ __launch_bounds__(256) void k_inv(const int* __restrict__ deg,
                                             float* __restrict__ inv) {
  int i = blockIdx.x * 256 + threadIdx.x;
  if (i < N_NODES) {
    int d = deg[i];
    inv[i] = d > 0 ? 1.0f / (float)d : 0.0f;
  }
}

// ---------------- exclusive scan over degrees (single block, wave-shfl) ----------------
__global__ __launch_bounds__(1024) void k_scan(const int* __restrict__ deg,
                                               int* __restrict__ rowptr,
                                               int* __restrict__ cursor) {
  __shared__ int s_wsum[16];
  __shared__ int s_carry;
  const int lane = threadIdx.x & 63;
  const int wid = threadIdx.x >> 6;
  if (threadIdx.x == 0) s_carry = 0;
  __syncthreads();
  for (int base = 0; base < N_NODES; base += 1024) {
    int i = base + threadIdx.x;
    int v = (i < N_NODES) ? deg[i] : 0;
    int x = v;  // inclusive wave scan
#pragma unroll
    for (int off = 1; off < 64; off <<= 1) {
      int t = __shfl_up(x, off);
      if (lane >= off) x += t;
    }
    if (lane == 63) s_wsum[wid] = x;
    __syncthreads();
    if (wid == 0 && lane < 16) {
      int ws = s_wsum[lane];
      int y = ws;
#pragma unroll
      for (int off = 1; off < 16; off <<= 1) {
        int t = __shfl_up(y, off);
        if (lane >= off) y += t;
      }
      s_wsum[lane] = y - ws;  // exclusive wave offsets
    }
    __syncthreads();
    int t = s_carry + s_wsum[wid] + (x - v);
    if (i < N_NODES) { rowptr[i] = t; cursor[i] = t; }
    __syncthreads();
    if (threadIdx.x == 1023) s_carry = t + v;
    __syncthreads();
  }
  if (threadIdx.x == 0) rowptr[N_NODES] = s_carry;
}

// ---------------- CSR fill ----------------
__global__ __launch_bounds__(256) void k_fill(const int* __restrict__ src,
                                              const int* __restrict__ dst,
                                              int* __restrict__ cursor,
                                              int* __restrict__ csr) {
  int e = blockIdx.x * 256 + threadIdx.x;
  if (e < N_EDGES) {
    int pos = atomicAdd(&cursor[dst[e]], 1);
    csr[pos] = src[e];
  }
}

// ---------------- gather aggregation: wave per node ----------------
template <int D>
__global__ __launch_bounds__(256) void k_agg(const int* __restrict__ rowptr,
                                             const int* __restrict__ csr,
                                             const float* __restrict__ feat,
                                             const float* __restrict__ inv,
                                             float* __restrict__ out) {
  const int lane = threadIdx.x & 63;
  const int n = blockIdx.x * 4 + (threadIdx.x >> 6);  // grid exact: 25000*4
  const int beg = rowptr[n], end = rowptr[n + 1];
  if (D == 64) {
    float acc = 0.0f;
    int j = beg;
    for (; j + 4 <= end; j += 4) {
      int s0 = csr[j], s1 = csr[j + 1], s2 = csr[j + 2], s3 = csr[j + 3];
      float f0 = feat[(long)s0 * 64 + lane];
      float f1 = feat[(long)s1 * 64 + lane];
      float f2 = feat[(long)s2 * 64 + lane];
      float f3 = feat[(long)s3 * 64 + lane];
      acc += f0; acc += f1; acc += f2; acc += f3;
    }
    for (; j < end; ++j) acc += feat[(long)csr[j] * 64 + lane];
    out[(long)n * 64 + lane] = acc * inv[n];
  } else {
    float2 acc = {0.0f, 0.0f};
    int j = beg;
    for (; j + 4 <= end; j += 4) {
      int s0 = csr[j], s1 = csr[j + 1], s2 = csr[j + 2], s3 = csr[j + 3];
      float2 f0 = *(const float2*)&feat[(long)s0 * 128 + lane * 2];
      float2 f1 = *(const float2*)&feat[(long)s1 * 128 + lane * 2];
      float2 f2 = *(const float2*)&feat[(long)s2 * 128 + lane * 2];
      float2 f3 = *(const float2*)&feat[(long)s3 * 128 + lane * 2];
      acc.x += f0.x; acc.y += f0.y;
      acc.x += f1.x; acc.y += f1.y;
      acc.x += f2.x; acc.y += f2.y;
      acc.x += f3.x; acc.y += f3.y;
    }
    for (; j < end; ++j) {
      float2 f = *(const float2*)&feat[(long)csr[j] * 128 + lane * 2];
      acc.x += f.x; acc.y += f.y;
    }
    float iv = inv[n];
    float2 o = {acc.x * iv, acc.y * iv};
    *(float2*)&out[(long)n * 128 + lane * 2] = o;
  }
}

// ---------------- register-tiled fused SAGE layer (row-major LDS, broadcast reads) ----------------
// Block: 256 thr, tile 32 rows x 128 cols, 4x4 per thread.
// out = act(mean@wl + bl + xin@wr); if DO_UV additionally:
//   z = that result, u = z@dw1[0:128] -> out, v = z@dw1[128:256] -> vout.
// Inputs fully staged to LDS before any global write, so out may alias mean/xin rows.
template <int K, bool RELU, bool DO_UV>
__global__ __launch_bounds__(256) void k_layer(
    const float* __restrict__ mean, const float* __restrict__ xin,
    const float* __restrict__ wl, const float* __restrict__ bl,
    const float* __restrict__ wr, const float* __restrict__ dw1,
    float* __restrict__ out, float* __restrict__ vout) {
  // row-major tiles: LDS reads in the k-loop are wave-broadcasts (conflict-free),
  // staging writes are contiguous b128 (conflict-free). No transpose, no pad.
  __shared__ float s_a[32][K];  // mean tile; reused as z tile in DO_UV phase 2 (K==HID there)
  __shared__ float s_x[32][K];  // xin tile
  const int tx = threadIdx.x & 31;  // col group
  const int ty = threadIdx.x >> 5;  // row group
  const int row0 = blockIdx.x * 32; // grid exact: 3125*32 = 100000
  const int c0 = tx * 4;
  const int r0 = ty * 4;

  {
    constexpr int KG = K / 4;
    for (int t = threadIdx.x; t < 32 * KG; t += 256) {
      int r = t / KG, kg = t % KG;
      *(float4*)&s_a[r][kg * 4] = *(const float4*)&mean[(long)(row0 + r) * K + kg * 4];
      *(float4*)&s_x[r][kg * 4] = *(const float4*)&xin[(long)(row0 + r) * K + kg * 4];
    }
  }
  __syncthreads();

  float acc[4][4];
  {
    float4 bv = *(const float4*)&bl[c0];
#pragma unroll
    for (int j = 0; j < 4; ++j) {
      acc[j][0] = bv.x; acc[j][1] = bv.y; acc[j][2] = bv.z; acc[j][3] = bv.w;
    }
  }

  for (int kk = 0; kk < K; kk += 4) {
    float a4[4][4], x4[4][4];
#pragma unroll
    for (int j = 0; j < 4; ++j) {
      float4 av = *(const float4*)&s_a[r0 + j][kk];
      float4 xv = *(const float4*)&s_x[r0 + j][kk];
      a4[j][0] = av.x; a4[j][1] = av.y; a4[j][2] = av.z; a4[j][3] = av.w;
      x4[j][0] = xv.x; x4[j][1] = xv.y; x4[j][2] = xv.z; x4[j][3] = xv.w;
    }
#pragma unroll
    for (int t = 0; t < 4; ++t) {
      float4 wlv = *(const float4*)&wl[(long)(kk + t) * HID + c0];
      float4 wrv = *(const float4*)&wr[(long)(kk + t) * HID + c0];
      float wli[4] = {wlv.x, wlv.y, wlv.z, wlv.w};
      float wri[4] = {wrv.x, wrv.y, wrv.z, wrv.w};
#pragma unroll
      for (int j = 0; j < 4; ++j)
#pragma unroll
        for (int i = 0; i < 4; ++i)
          acc[j][i] = fmaf(a4[j][t], wli[i], fmaf(x4[j][t], wri[i], acc[j][i]));
    }
  }

  if (!DO_UV) {
#pragma unroll
    for (int j = 0; j < 4; ++j) {
      float4 o;
      o.x = RELU ? fmaxf(acc[j][0], 0.0f) : acc[j][0];
      o.y = RELU ? fmaxf(acc[j][1], 0.0f) : acc[j][1];
      o.z = RELU ? fmaxf(acc[j][2], 0.0f) : acc[j][2];
      o.w = RELU ? fmaxf(acc[j][3], 0.0f) : acc[j][3];
      *(float4*)&out[(long)(row0 + r0 + j) * HID + c0] = o;
    }
  } else {
    // stash z row-major into s_a (contiguous b128 row writes, conflict-free)
    __syncthreads();  // all phase-1 LDS reads done before overwrite
#pragma unroll
    for (int j = 0; j < 4; ++j) {
      float4 o = {acc[j][0], acc[j][1], acc[j][2], acc[j][3]};
      *(float4*)&s_a[r0 + j][c0] = o;
    }
    __syncthreads();

    float u[4][4], v[4][4];
#pragma unroll
    for (int j = 0; j < 4; ++j)
#pragma unroll
      for (int i = 0; i < 4; ++i) { u[j][i] = 0.0f; v[j][i] = 0.0f; }

    for (int kk = 0; kk < HID; kk += 4) {
      float z4[4][4];
#pragma unroll
      for (int j = 0; j < 4; ++j) {
        float4 zv = *(const float4*)&s_a[r0 + j][kk];
        z4[j][0] = zv.x; z4[j][1] = zv.y; z4[j][2] = zv.z; z4[j][3] = zv.w;
      }
#pragma unroll
      for (int t = 0; t < 4; ++t) {
        float4 w1v = *(const float4*)&dw1[(long)(kk + t) * HID + c0];
        float4 w2v = *(const float4*)&dw1[(long)(kk + t + HID) * HID + c0];
        float w1i[4] = {w1v.x, w1v.y, w1v.z, w1v.w};
        float w2i[4] = {w2v.x, w2v.y, w2v.z, w2v.w};
#pragma unroll
        for (int j = 0; j < 4; ++j)
#pragma unroll
          for (int i = 0; i < 4; ++i) {
            u[j][i] = fmaf(z4[j][t], w1i[i], u[j][i]);
            v[j][i] = fmaf(z4[j][t], w2i[i], v[j][i]);
          }
      }
    }

#pragma unroll
    for (int j = 0; j < 4; ++j) {
      float4 ou = {u[j][0], u[j][1], u[j][2], u[j][3]};
      float4 ov = {v[j][0], v[j][1], v[j][2], v[j][3]};
      *(float4*)&out[(long)(row0 + r0 + j) * HID + c0] = ou;
      *(float4*)&vout[(long)(row0 + r0 + j) * HID + c0] = ov;
    }
  }
}

// ---------------- per-label-edge decoder ----------------
__global__ __launch_bounds__(256) void k_edge(const int* __restrict__ ls,
                                              const int* __restrict__ ld,
                                              const float* __restrict__ u,
                                              const float* __restrict__ v,
                                              const float* __restrict__ db1,
                                              const float* __restrict__ dw2,
                                              const float* __restrict__ db2,
                                              float* __restrict__ out) {
  int lane = threadIdx.x & 63;
  long e = (long)blockIdx.x * 4 + (threadIdx.x >> 6);  // grid exact: 125000*4
  int s = ls[e], d = ld[e];
  const float2 uu = *(const float2*)&u[(long)s * HID + lane * 2];
  const float2 vv = *(const float2*)&v[(long)d * HID + lane * 2];
  const float2 b = *(const float2*)&db1[lane * 2];
  const float2 w = *(const float2*)&dw2[lane * 2];
  float h0 = fmaxf(uu.x + vv.x + b.x, 0.0f);
  float h1 = fmaxf(uu.y + vv.y + b.y, 0.0f);
  float sum = h0 * w.x + h1 * w.y;
#pragma unroll
  for (int o = 32; o > 0; o >>= 1) sum += __shfl_down(sum, o);
  if (lane == 0) out[e] = sum + db2[0];
}

extern "C" void kernel_launch(void* const* d_in, const int* in_sizes, int n_in,
                              void* d_out, int out_size, void* d_ws, size_t ws_size,
                              hipStream_t stream) {
  const float* x   = (const float*)d_in[0];
  const int*   ei  = (const int*)d_in[1];
  const int*   eli = (const int*)d_in[2];
  const float* w1l = (const float*)d_in[3];
  const float* b1l = (const float*)d_in[4];
  const float* w1r = (const float*)d_in[5];
  const float* w2l = (const float*)d_in[6];
  const float* b2l = (const float*)d_in[7];
  const float* w2r = (const float*)d_in[8];
  const float* dw1 = (const float*)d_in[9];
  const float* db1 = (const float*)d_in[10];
  const float* dw2 = (const float*)d_in[11];
  const float* db2 = (const float*)d_in[12];
  float* out = (float*)d_out;

  // ---- workspace layout ----
  float* ws     = (float*)d_ws;
  float* inv    = ws;                             // 100000 f
  int*   deg_i  = (int*)(ws + 100000);            // 100000 i
  int*   rowptr = deg_i + 100000;                 // 100008 i
  int*   cursor = rowptr + 100008;                // 100000 i
  int*   csr    = cursor + 100000;                // 1600000 i
  float* cbuf   = (float*)(csr + 1600000);        // N*HID f (mean1/mean2 -> u)
  float* hbuf   = cbuf + (size_t)N_NODES * HID;   // N*HID f (h -> v)

  const int* srcp = ei;
  const int* dstp = ei + N_EDGES;
  const int* lsp  = eli;
  const int* ldp  = eli + N_LBL;

  // ---- CSR build ----
  hipMemsetAsync(deg_i, 0, N_NODES * sizeof(int), stream);
  k_deg<<<N_EDGES / 256, 256, 0, stream>>>(dstp, deg_i);
  k_inv<<<(N_NODES + 255) / 256, 256, 0, stream>>>(deg_i, inv);
  k_scan<<<1, 1024, 0, stream>>>(deg_i, rowptr, cursor);
  k_fill<<<N_EDGES / 256, 256, 0, stream>>>(srcp, dstp, cursor, csr);

  // ---- layer 1: mean1 -> cbuf (64 cols); h = relu(...) -> hbuf ----
  k_agg<64><<<N_NODES / 4, 256, 0, stream>>>(rowptr, csr, x, inv, cbuf);
  k_layer<64, true, false><<<N_NODES / 32, 256, 0, stream>>>(
      cbuf, x, w1l, b1l, w1r, nullptr, hbuf, nullptr);

  // ---- layer 2 + decoder-precompute fused:
  //      mean2 -> cbuf; z in LDS; u -> cbuf, v -> hbuf ----
  k_agg<128><<<N_NODES / 4, 256, 0, stream>>>(rowptr, csr, hbuf, inv, cbuf);
  k_layer<128, false, true><<<N_NODES / 32, 256, 0, stream>>>(
      cbuf, hbuf, w2l, b2l, w2r, dw1, cbuf, hbuf);

  // ---- decoder edge MLP ----
  k_edge<<<N_LBL / 4, 256, 0, stream>>>(lsp, ldp, cbuf, hbuf, db1, dw2, db2, out);
}

// Round 5
// 881.253 us; speedup vs baseline: 1.0074x; 1.0074x over previous
//
#include <hip/hip_runtime.h>

#define N_NODES 100000
#define D_IN 64
#define HID 128
#define N_EDGES 1600000
#define N_LBL 500000

// ---------------- degree histogram (int) ----------------
__global__ __launch_bounds__(256) void k_deg(const int* __restrict__ dst,
                                             int* __restrict__ deg) {
  int e = blockIdx.x * 256 + threadIdx.x;
  if (e < N_EDGES) atomicAdd(&deg[dst[e]], 1);
}

__global__ __launch_bounds__(256) void k_inv(const int* __restrict__ deg,
                                             float* __restrict__ inv) {
  int i = blockIdx.x * 256 + threadIdx.x;
  if (i < N_NODES) {
    int d = deg[i];
    inv[i] = d > 0 ? 1.0f / (float)d : 0.0f;
  }
}

// ---------------- exclusive scan over degrees (single block, wave-shfl) ----------------
__global__ __launch_bounds__(1024) void k_scan(const int* __restrict__ deg,
                                               int* __restrict__ rowptr,
                                               int* __restrict__ cursor) {
  __shared__ int s_wsum[16];
  __shared__ int s_carry;
  const int lane = threadIdx.x & 63;
  const int wid = threadIdx.x >> 6;
  if (threadIdx.x == 0) s_carry = 0;
  __syncthreads();
  for (int base = 0; base < N_NODES; base += 1024) {
    int i = base + threadIdx.x;
    int v = (i < N_NODES) ? deg[i] : 0;
    int x = v;  // inclusive wave scan
#pragma unroll
    for (int off = 1; off < 64; off <<= 1) {
      int t = __shfl_up(x, off);
      if (lane >= off) x += t;
    }
    if (lane == 63) s_wsum[wid] = x;
    __syncthreads();
    if (wid == 0 && lane < 16) {
      int ws = s_wsum[lane];
      int y = ws;
#pragma unroll
      for (int off = 1; off < 16; off <<= 1) {
        int t = __shfl_up(y, off);
        if (lane >= off) y += t;
      }
      s_wsum[lane] = y - ws;  // exclusive wave offsets
    }
    __syncthreads();
    int t = s_carry + s_wsum[wid] + (x - v);
    if (i < N_NODES) { rowptr[i] = t; cursor[i] = t; }
    __syncthreads();
    if (threadIdx.x == 1023) s_carry = t + v;
    __syncthreads();
  }
  if (threadIdx.x == 0) rowptr[N_NODES] = s_carry;
}

// ---------------- CSR fill ----------------
__global__ __launch_bounds__(256) void k_fill(const int* __restrict__ src,
                                              const int* __restrict__ dst,
                                              int* __restrict__ cursor,
                                              int* __restrict__ csr) {
  int e = blockIdx.x * 256 + threadIdx.x;
  if (e < N_EDGES) {
    int pos = atomicAdd(&cursor[dst[e]], 1);
    csr[pos] = src[e];
  }
}

// ---------------- gather aggregation: wave per node ----------------
template <int D>
__global__ __launch_bounds__(256) void k_agg(const int* __restrict__ rowptr,
                                             const int* __restrict__ csr,
                                             const float* __restrict__ feat,
                                             const float* __restrict__ inv,
                                             float* __restrict__ out) {
  const int lane = threadIdx.x & 63;
  const int n = blockIdx.x * 4 + (threadIdx.x >> 6);  // grid exact: 25000*4
  const int beg = rowptr[n], end = rowptr[n + 1];
  if (D == 64) {
    float acc = 0.0f;
    int j = beg;
    for (; j + 4 <= end; j += 4) {
      int s0 = csr[j], s1 = csr[j + 1], s2 = csr[j + 2], s3 = csr[j + 3];
      float f0 = feat[(long)s0 * 64 + lane];
      float f1 = feat[(long)s1 * 64 + lane];
      float f2 = feat[(long)s2 * 64 + lane];
      float f3 = feat[(long)s3 * 64 + lane];
      acc += f0; acc += f1; acc += f2; acc += f3;
    }
    for (; j < end; ++j) acc += feat[(long)csr[j] * 64 + lane];
    out[(long)n * 64 + lane] = acc * inv[n];
  } else {
    float2 acc = {0.0f, 0.0f};
    int j = beg;
    for (; j + 4 <= end; j += 4) {
      int s0 = csr[j], s1 = csr[j + 1], s2 = csr[j + 2], s3 = csr[j + 3];
      float2 f0 = *(const float2*)&feat[(long)s0 * 128 + lane * 2];
      float2 f1 = *(const float2*)&feat[(long)s1 * 128 + lane * 2];
      float2 f2 = *(const float2*)&feat[(long)s2 * 128 + lane * 2];
      float2 f3 = *(const float2*)&feat[(long)s3 * 128 + lane * 2];
      acc.x += f0.x; acc.y += f0.y;
      acc.x += f1.x; acc.y += f1.y;
      acc.x += f2.x; acc.y += f2.y;
      acc.x += f3.x; acc.y += f3.y;
    }
    for (; j < end; ++j) {
      float2 f = *(const float2*)&feat[(long)csr[j] * 128 + lane * 2];
      acc.x += f.x; acc.y += f.y;
    }
    float iv = inv[n];
    float2 o = {acc.x * iv, acc.y * iv};
    *(float2*)&out[(long)n * 128 + lane * 2] = o;
  }
}

// ---------------- register-tiled fused SAGE layer ----------------
// Block: 128 thr, tile 32 rows x 128 cols, 4 rows x 8 cols per thread.
// Per 4-k iter: 8 ds_read_b128 (A) vs 512 VALU cyc -> VALU-bound.
// out = act(mean@wl + bl + xin@wr); if DO_UV additionally:
//   z = that result, u = z@dw1[0:128] -> out, v = z@dw1[128:256] -> vout.
// Inputs fully staged to LDS before any global write, so out may alias mean/xin rows.
template <int K, bool RELU, bool DO_UV>
__global__ __launch_bounds__(128) void k_layer(
    const float* __restrict__ mean, const float* __restrict__ xin,
    const float* __restrict__ wl, const float* __restrict__ bl,
    const float* __restrict__ wr, const float* __restrict__ dw1,
    float* __restrict__ out, float* __restrict__ vout) {
  __shared__ float s_a[32][K];  // mean tile; reused as z tile in DO_UV phase 2 (K==HID there)
  __shared__ float s_x[32][K];  // xin tile
  const int tx = threadIdx.x & 15;  // 16 col groups of 8
  const int ty = threadIdx.x >> 4;  // 8 row groups of 4
  const int row0 = blockIdx.x * 32; // grid exact: 3125*32 = 100000
  const int c0 = tx * 8;
  const int r0 = ty * 4;

  {
    constexpr int KG = K / 4;
    for (int t = threadIdx.x; t < 32 * KG; t += 128) {
      int r = t / KG, kg = t % KG;
      *(float4*)&s_a[r][kg * 4] = *(const float4*)&mean[(long)(row0 + r) * K + kg * 4];
      *(float4*)&s_x[r][kg * 4] = *(const float4*)&xin[(long)(row0 + r) * K + kg * 4];
    }
  }
  __syncthreads();

  float acc[4][8];
  {
    float4 b0 = *(const float4*)&bl[c0];
    float4 b1 = *(const float4*)&bl[c0 + 4];
#pragma unroll
    for (int j = 0; j < 4; ++j) {
      acc[j][0] = b0.x; acc[j][1] = b0.y; acc[j][2] = b0.z; acc[j][3] = b0.w;
      acc[j][4] = b1.x; acc[j][5] = b1.y; acc[j][6] = b1.z; acc[j][7] = b1.w;
    }
  }

  for (int kk = 0; kk < K; kk += 4) {
    float a4[4][4], x4[4][4];  // [j][t]
#pragma unroll
    for (int j = 0; j < 4; ++j) {
      float4 av = *(const float4*)&s_a[r0 + j][kk];
      float4 xv = *(const float4*)&s_x[r0 + j][kk];
      a4[j][0] = av.x; a4[j][1] = av.y; a4[j][2] = av.z; a4[j][3] = av.w;
      x4[j][0] = xv.x; x4[j][1] = xv.y; x4[j][2] = xv.z; x4[j][3] = xv.w;
    }
#pragma unroll
    for (int t = 0; t < 4; ++t) {
      float4 wl0 = *(const float4*)&wl[(long)(kk + t) * HID + c0];
      float4 wl1 = *(const float4*)&wl[(long)(kk + t) * HID + c0 + 4];
      float4 wr0 = *(const float4*)&wr[(long)(kk + t) * HID + c0];
      float4 wr1 = *(const float4*)&wr[(long)(kk + t) * HID + c0 + 4];
      float wli[8] = {wl0.x, wl0.y, wl0.z, wl0.w, wl1.x, wl1.y, wl1.z, wl1.w};
      float wri[8] = {wr0.x, wr0.y, wr0.z, wr0.w, wr1.x, wr1.y, wr1.z, wr1.w};
#pragma unroll
      for (int j = 0; j < 4; ++j)
#pragma unroll
        for (int i = 0; i < 8; ++i)
          acc[j][i] = fmaf(a4[j][t], wli[i], fmaf(x4[j][t], wri[i], acc[j][i]));
    }
  }

  if (!DO_UV) {
#pragma unroll
    for (int j = 0; j < 4; ++j) {
      float4 o0, o1;
      o0.x = RELU ? fmaxf(acc[j][0], 0.0f) : acc[j][0];
      o0.y = RELU ? fmaxf(acc[j][1], 0.0f) : acc[j][1];
      o0.z = RELU ? fmaxf(acc[j][2], 0.0f) : acc[j][2];
      o0.w = RELU ? fmaxf(acc[j][3], 0.0f) : acc[j][3];
      o1.x = RELU ? fmaxf(acc[j][4], 0.0f) : acc[j][4];
      o1.y = RELU ? fmaxf(acc[j][5], 0.0f) : acc[j][5];
      o1.z = RELU ? fmaxf(acc[j][6], 0.0f) : acc[j][6];
      o1.w = RELU ? fmaxf(acc[j][7], 0.0f) : acc[j][7];
      *(float4*)&out[(long)(row0 + r0 + j) * HID + c0] = o0;
      *(float4*)&out[(long)(row0 + r0 + j) * HID + c0 + 4] = o1;
    }
  } else {
    // stash z row-major into s_a (contiguous b128 row writes)
    __syncthreads();  // all phase-1 LDS reads done before overwrite
#pragma unroll
    for (int j = 0; j < 4; ++j) {
      float4 o0 = {acc[j][0], acc[j][1], acc[j][2], acc[j][3]};
      float4 o1 = {acc[j][4], acc[j][5], acc[j][6], acc[j][7]};
      *(float4*)&s_a[r0 + j][c0] = o0;
      *(float4*)&s_a[r0 + j][c0 + 4] = o1;
    }
    __syncthreads();

    float u[4][8], v[4][8];
#pragma unroll
    for (int j = 0; j < 4; ++j)
#pragma unroll
      for (int i = 0; i < 8; ++i) { u[j][i] = 0.0f; v[j][i] = 0.0f; }

    for (int kk = 0; kk < HID; kk += 4) {
      float z4[4][4];
#pragma unroll
      for (int j = 0; j < 4; ++j) {
        float4 zv = *(const float4*)&s_a[r0 + j][kk];
        z4[j][0] = zv.x; z4[j][1] = zv.y; z4[j][2] = zv.z; z4[j][3] = zv.w;
      }
#pragma unroll
      for (int t = 0; t < 4; ++t) {
        float4 w10 = *(const float4*)&dw1[(long)(kk + t) * HID + c0];
        float4 w11 = *(const float4*)&dw1[(long)(kk + t) * HID + c0 + 4];
        float4 w20 = *(const float4*)&dw1[(long)(kk + t + HID) * HID + c0];
        float4 w21 = *(const float4*)&dw1[(long)(kk + t + HID) * HID + c0 + 4];
        float w1i[8] = {w10.x, w10.y, w10.z, w10.w, w11.x, w11.y, w11.z, w11.w};
        float w2i[8] = {w20.x, w20.y, w20.z, w20.w, w21.x, w21.y, w21.z, w21.w};
#pragma unroll
        for (int j = 0; j < 4; ++j)
#pragma unroll
          for (int i = 0; i < 8; ++i) {
            u[j][i] = fmaf(z4[j][t], w1i[i], u[j][i]);
            v[j][i] = fmaf(z4[j][t], w2i[i], v[j][i]);
          }
      }
    }

#pragma unroll
    for (int j = 0; j < 4; ++j) {
      float4 ou0 = {u[j][0], u[j][1], u[j][2], u[j][3]};
      float4 ou1 = {u[j][4], u[j][5], u[j][6], u[j][7]};
      float4 ov0 = {v[j][0], v[j][1], v[j][2], v[j][3]};
      float4 ov1 = {v[j][4], v[j][5], v[j][6], v[j][7]};
      *(float4*)&out[(long)(row0 + r0 + j) * HID + c0] = ou0;
      *(float4*)&out[(long)(row0 + r0 + j) * HID + c0 + 4] = ou1;
      *(float4*)&vout[(long)(row0 + r0 + j) * HID + c0] = ov0;
      *(float4*)&vout[(long)(row0 + r0 + j) * HID + c0 + 4] = ov1;
    }
  }
}

// ---------------- per-label-edge decoder ----------------
__global__ __launch_bounds__(256) void k_edge(const int* __restrict__ ls,
                                              const int* __restrict__ ld,
                                              const float* __restrict__ u,
                                              const float* __restrict__ v,
                                              const float* __restrict__ db1,
                                              const float* __restrict__ dw2,
                                              const float* __restrict__ db2,
                                              float* __restrict__ out) {
  int lane = threadIdx.x & 63;
  long e = (long)blockIdx.x * 4 + (threadIdx.x >> 6);  // grid exact: 125000*4
  int s = ls[e], d = ld[e];
  const float2 uu = *(const float2*)&u[(long)s * HID + lane * 2];
  const float2 vv = *(const float2*)&v[(long)d * HID + lane * 2];
  const float2 b = *(const float2*)&db1[lane * 2];
  const float2 w = *(const float2*)&dw2[lane * 2];
  float h0 = fmaxf(uu.x + vv.x + b.x, 0.0f);
  float h1 = fmaxf(uu.y + vv.y + b.y, 0.0f);
  float sum = h0 * w.x + h1 * w.y;
#pragma unroll
  for (int o = 32; o > 0; o >>= 1) sum += __shfl_down(sum, o);
  if (lane == 0) out[e] = sum + db2[0];
}

extern "C" void kernel_launch(void* const* d_in, const int* in_sizes, int n_in,
                              void* d_out, int out_size, void* d_ws, size_t ws_size,
                              hipStream_t stream) {
  const float* x   = (const float*)d_in[0];
  const int*   ei  = (const int*)d_in[1];
  const int*   eli = (const int*)d_in[2];
  const float* w1l = (const float*)d_in[3];
  const float* b1l = (const float*)d_in[4];
  const float* w1r = (const float*)d_in[5];
  const float* w2l = (const float*)d_in[6];
  const float* b2l = (const float*)d_in[7];
  const float* w2r = (const float*)d_in[8];
  const float* dw1 = (const float*)d_in[9];
  const float* db1 = (const float*)d_in[10];
  const float* dw2 = (const float*)d_in[11];
  const float* db2 = (const float*)d_in[12];
  float* out = (float*)d_out;

  // ---- workspace layout ----
  float* ws     = (float*)d_ws;
  float* inv    = ws;                             // 100000 f
  int*   deg_i  = (int*)(ws + 100000);            // 100000 i
  int*   rowptr = deg_i + 100000;                 // 100008 i
  int*   cursor = rowptr + 100008;                // 100000 i
  int*   csr    = cursor + 100000;                // 1600000 i
  float* cbuf   = (float*)(csr + 1600000);        // N*HID f (mean1/mean2 -> u)
  float* hbuf   = cbuf + (size_t)N_NODES * HID;   // N*HID f (h -> v)

  const int* srcp = ei;
  const int* dstp = ei + N_EDGES;
  const int* lsp  = eli;
  const int* ldp  = eli + N_LBL;

  // ---- CSR build ----
  hipMemsetAsync(deg_i, 0, N_NODES * sizeof(int), stream);
  k_deg<<<N_EDGES / 256, 256, 0, stream>>>(dstp, deg_i);
  k_inv<<<(N_NODES + 255) / 256, 256, 0, stream>>>(deg_i, inv);
  k_scan<<<1, 1024, 0, stream>>>(deg_i, rowptr, cursor);
  k_fill<<<N_EDGES / 256, 256, 0, stream>>>(srcp, dstp, cursor, csr);

  // ---- layer 1: mean1 -> cbuf (64 cols); h = relu(...) -> hbuf ----
  k_agg<64><<<N_NODES / 4, 256, 0, stream>>>(rowptr, csr, x, inv, cbuf);
  k_layer<64, true, false><<<N_NODES / 32, 128, 0, stream>>>(
      cbuf, x, w1l, b1l, w1r, nullptr, hbuf, nullptr);

  // ---- layer 2 + decoder-precompute fused:
  //      mean2 -> cbuf; z in LDS; u -> cbuf, v -> hbuf ----
  k_agg<128><<<N_NODES / 4, 256, 0, stream>>>(rowptr, csr, hbuf, inv, cbuf);
  k_layer<128, false, true><<<N_NODES / 32, 128, 0, stream>>>(
      cbuf, hbuf, w2l, b2l, w2r, dw1, cbuf, hbuf);

  // ---- decoder edge MLP ----
  k_edge<<<N_LBL / 4, 256, 0, stream>>>(lsp, ldp, cbuf, hbuf, db1, dw2, db2, out);
}

// Round 6
// 848.381 us; speedup vs baseline: 1.0464x; 1.0387x over previous
//
#include <hip/hip_runtime.h>

#define N_NODES 100000
#define D_IN 64
#define HID 128
#define N_EDGES 1600000
#define N_LBL 500000

// ---------------- degree histogram (int) ----------------
__global__ __launch_bounds__(256) void k_deg(const int* __restrict__ dst,
                                             int* __restrict__ deg) {
  int e = blockIdx.x * 256 + threadIdx.x;
  if (e < N_EDGES) atomicAdd(&deg[dst[e]], 1);
}

__global__ __launch_bounds__(256) void k_inv(const int* __restrict__ deg,
                                             float* __restrict__ inv) {
  int i = blockIdx.x * 256 + threadIdx.x;
  if (i < N_NODES) {
    int d = deg[i];
    inv[i] = d > 0 ? 1.0f / (float)d : 0.0f;
  }
}

// ---------------- exclusive scan over degrees (single block, wave-shfl) ----------------
__global__ __launch_bounds__(1024) void k_scan(const int* __restrict__ deg,
                                               int* __restrict__ rowptr,
                                               int* __restrict__ cursor) {
  __shared__ int s_wsum[16];
  __shared__ int s_carry;
  const int lane = threadIdx.x & 63;
  const int wid = threadIdx.x >> 6;
  if (threadIdx.x == 0) s_carry = 0;
  __syncthreads();
  for (int base = 0; base < N_NODES; base += 1024) {
    int i = base + threadIdx.x;
    int v = (i < N_NODES) ? deg[i] : 0;
    int x = v;  // inclusive wave scan
#pragma unroll
    for (int off = 1; off < 64; off <<= 1) {
      int t = __shfl_up(x, off);
      if (lane >= off) x += t;
    }
    if (lane == 63) s_wsum[wid] = x;
    __syncthreads();
    if (wid == 0 && lane < 16) {
      int ws = s_wsum[lane];
      int y = ws;
#pragma unroll
      for (int off = 1; off < 16; off <<= 1) {
        int t = __shfl_up(y, off);
        if (lane >= off) y += t;
      }
      s_wsum[lane] = y - ws;  // exclusive wave offsets
    }
    __syncthreads();
    int t = s_carry + s_wsum[wid] + (x - v);
    if (i < N_NODES) { rowptr[i] = t; cursor[i] = t; }
    __syncthreads();
    if (threadIdx.x == 1023) s_carry = t + v;
    __syncthreads();
  }
  if (threadIdx.x == 0) rowptr[N_NODES] = s_carry;
}

// ---------------- CSR fill ----------------
__global__ __launch_bounds__(256) void k_fill(const int* __restrict__ src,
                                              const int* __restrict__ dst,
                                              int* __restrict__ cursor,
                                              int* __restrict__ csr) {
  int e = blockIdx.x * 256 + threadIdx.x;
  if (e < N_EDGES) {
    int pos = atomicAdd(&cursor[dst[e]], 1);
    csr[pos] = src[e];
  }
}

// ---------------- gather aggregation: wave per node ----------------
template <int D>
__global__ __launch_bounds__(256) void k_agg(const int* __restrict__ rowptr,
                                             const int* __restrict__ csr,
                                             const float* __restrict__ feat,
                                             const float* __restrict__ inv,
                                             float* __restrict__ out) {
  const int lane = threadIdx.x & 63;
  const int n = blockIdx.x * 4 + (threadIdx.x >> 6);  // grid exact: 25000*4
  const int beg = rowptr[n], end = rowptr[n + 1];
  if (D == 64) {
    float acc = 0.0f;
    int j = beg;
    for (; j + 4 <= end; j += 4) {
      int s0 = csr[j], s1 = csr[j + 1], s2 = csr[j + 2], s3 = csr[j + 3];
      float f0 = feat[(long)s0 * 64 + lane];
      float f1 = feat[(long)s1 * 64 + lane];
      float f2 = feat[(long)s2 * 64 + lane];
      float f3 = feat[(long)s3 * 64 + lane];
      acc += f0; acc += f1; acc += f2; acc += f3;
    }
    for (; j < end; ++j) acc += feat[(long)csr[j] * 64 + lane];
    out[(long)n * 64 + lane] = acc * inv[n];
  } else {
    float2 acc = {0.0f, 0.0f};
    int j = beg;
    for (; j + 4 <= end; j += 4) {
      int s0 = csr[j], s1 = csr[j + 1], s2 = csr[j + 2], s3 = csr[j + 3];
      float2 f0 = *(const float2*)&feat[(long)s0 * 128 + lane * 2];
      float2 f1 = *(const float2*)&feat[(long)s1 * 128 + lane * 2];
      float2 f2 = *(const float2*)&feat[(long)s2 * 128 + lane * 2];
      float2 f3 = *(const float2*)&feat[(long)s3 * 128 + lane * 2];
      acc.x += f0.x; acc.y += f0.y;
      acc.x += f1.x; acc.y += f1.y;
      acc.x += f2.x; acc.y += f2.y;
      acc.x += f3.x; acc.y += f3.y;
    }
    for (; j < end; ++j) {
      float2 f = *(const float2*)&feat[(long)csr[j] * 128 + lane * 2];
      acc.x += f.x; acc.y += f.y;
    }
    float iv = inv[n];
    float2 o = {acc.x * iv, acc.y * iv};
    *(float2*)&out[(long)n * 128 + lane * 2] = o;
  }
}

// ---------------- register-tiled fused SAGE layer ----------------
// Block: 256 thr, tile 64 rows x 128 cols, 8 rows x 4 cols per thread.
// A (mean, reused by all 32 col-groups) staged in LDS; X (no block reuse) read
// directly from global (broadcast within half-wave); weights from L2.
// Per 4-k iter/thread: 8 LDS b128 + 8 global b128 (X) + 8 global b128 (W), 256 FMAs.
// out = act(mean@wl + bl + xin@wr); if DO_UV additionally:
//   z = that result, u = z@dw1[0:128] -> out, v = z@dw1[128:256] -> vout.
// Aliasing safety: blocks are row-partitioned; out/vout stores happen only
// after __syncthreads() that follows all phase-1 reads of mean/xin rows.
template <int K, bool RELU, bool DO_UV>
__global__ __launch_bounds__(256) void k_layer(
    const float* __restrict__ mean, const float* __restrict__ xin,
    const float* __restrict__ wl, const float* __restrict__ bl,
    const float* __restrict__ wr, const float* __restrict__ dw1,
    float* __restrict__ out, float* __restrict__ vout) {
  static_assert(!DO_UV || K == HID, "z tile reuse requires K==HID");
  __shared__ float s_a[64][K];      // mean tile; reused as z tile in DO_UV phase 2
  const int tx = threadIdx.x & 31;  // 32 col groups of 4
  const int ty = threadIdx.x >> 5;  // 8 row groups of 8
  const int row0 = blockIdx.x * 64; // grid: ceil(100000/64) = 1563 (tail guarded)
  const int c0 = tx * 4;
  const int r0 = ty * 8;

  // stage mean tile (zero-fill OOB rows)
  {
    constexpr int KG = K / 4;
    for (int t = threadIdx.x; t < 64 * KG; t += 256) {
      int r = t / KG, kg = t % KG;
      long row = row0 + r;
      float4 v = {0.0f, 0.0f, 0.0f, 0.0f};
      if (row < N_NODES) v = *(const float4*)&mean[row * K + kg * 4];
      *(float4*)&s_a[r][kg * 4] = v;
    }
  }
  // per-thread X row offsets (OOB rows clamped to row 0; results discarded)
  int xoff[8];
#pragma unroll
  for (int j = 0; j < 8; ++j) {
    int row = row0 + r0 + j;
    xoff[j] = (row < N_NODES ? row : 0) * K;
  }
  __syncthreads();

  float acc[8][4];
  {
    float4 bv = *(const float4*)&bl[c0];
#pragma unroll
    for (int j = 0; j < 8; ++j) {
      acc[j][0] = bv.x; acc[j][1] = bv.y; acc[j][2] = bv.z; acc[j][3] = bv.w;
    }
  }

  for (int kk = 0; kk < K; kk += 4) {
    float A[8][4], X[8][4];
#pragma unroll
    for (int j = 0; j < 8; ++j) {
      float4 av = *(const float4*)&s_a[r0 + j][kk];
      A[j][0] = av.x; A[j][1] = av.y; A[j][2] = av.z; A[j][3] = av.w;
    }
#pragma unroll
    for (int j = 0; j < 8; ++j) {
      float4 xv = *(const float4*)&xin[xoff[j] + kk];
      X[j][0] = xv.x; X[j][1] = xv.y; X[j][2] = xv.z; X[j][3] = xv.w;
    }
#pragma unroll
    for (int t = 0; t < 4; ++t) {
      float4 wlv = *(const float4*)&wl[(long)(kk + t) * HID + c0];
      float4 wrv = *(const float4*)&wr[(long)(kk + t) * HID + c0];
      float WL[4] = {wlv.x, wlv.y, wlv.z, wlv.w};
      float WR[4] = {wrv.x, wrv.y, wrv.z, wrv.w};
#pragma unroll
      for (int j = 0; j < 8; ++j)
#pragma unroll
        for (int i = 0; i < 4; ++i)
          acc[j][i] = fmaf(A[j][t], WL[i], fmaf(X[j][t], WR[i], acc[j][i]));
    }
  }

  if (!DO_UV) {
#pragma unroll
    for (int j = 0; j < 8; ++j) {
      long row = row0 + r0 + j;
      if (row < N_NODES) {
        float4 o;
        o.x = RELU ? fmaxf(acc[j][0], 0.0f) : acc[j][0];
        o.y = RELU ? fmaxf(acc[j][1], 0.0f) : acc[j][1];
        o.z = RELU ? fmaxf(acc[j][2], 0.0f) : acc[j][2];
        o.w = RELU ? fmaxf(acc[j][3], 0.0f) : acc[j][3];
        *(float4*)&out[row * HID + c0] = o;
      }
    }
  } else {
    // stash z row-major into s_a (full-row spread across banks; 2-way max)
    __syncthreads();  // all phase-1 LDS reads (and xin reads) done before overwrite
#pragma unroll
    for (int j = 0; j < 8; ++j) {
      float4 o = {acc[j][0], acc[j][1], acc[j][2], acc[j][3]};
      *(float4*)&s_a[r0 + j][c0] = o;
    }
    __syncthreads();

    float u[8][4], v[8][4];
#pragma unroll
    for (int j = 0; j < 8; ++j)
#pragma unroll
      for (int i = 0; i < 4; ++i) { u[j][i] = 0.0f; v[j][i] = 0.0f; }

    for (int kk = 0; kk < HID; kk += 4) {
      float Z[8][4];
#pragma unroll
      for (int j = 0; j < 8; ++j) {
        float4 zv = *(const float4*)&s_a[r0 + j][kk];
        Z[j][0] = zv.x; Z[j][1] = zv.y; Z[j][2] = zv.z; Z[j][3] = zv.w;
      }
#pragma unroll
      for (int t = 0; t < 4; ++t) {
        float4 w1v = *(const float4*)&dw1[(long)(kk + t) * HID + c0];
        float4 w2v = *(const float4*)&dw1[(long)(kk + t + HID) * HID + c0];
        float W1[4] = {w1v.x, w1v.y, w1v.z, w1v.w};
        float W2[4] = {w2v.x, w2v.y, w2v.z, w2v.w};
#pragma unroll
        for (int j = 0; j < 8; ++j)
#pragma unroll
          for (int i = 0; i < 4; ++i) {
            u[j][i] = fmaf(Z[j][t], W1[i], u[j][i]);
            v[j][i] = fmaf(Z[j][t], W2[i], v[j][i]);
          }
      }
    }

#pragma unroll
    for (int j = 0; j < 8; ++j) {
      long row = row0 + r0 + j;
      if (row < N_NODES) {
        float4 ou = {u[j][0], u[j][1], u[j][2], u[j][3]};
        float4 ov = {v[j][0], v[j][1], v[j][2], v[j][3]};
        *(float4*)&out[row * HID + c0] = ou;
        *(float4*)&vout[row * HID + c0] = ov;
      }
    }
  }
}

// ---------------- per-label-edge decoder ----------------
__global__ __launch_bounds__(256) void k_edge(const int* __restrict__ ls,
                                              const int* __restrict__ ld,
                                              const float* __restrict__ u,
                                              const float* __restrict__ v,
                                              const float* __restrict__ db1,
                                              const float* __restrict__ dw2,
                                              const float* __restrict__ db2,
                                              float* __restrict__ out) {
  int lane = threadIdx.x & 63;
  long e = (long)blockIdx.x * 4 + (threadIdx.x >> 6);  // grid exact: 125000*4
  int s = ls[e], d = ld[e];
  const float2 uu = *(const float2*)&u[(long)s * HID + lane * 2];
  const float2 vv = *(const float2*)&v[(long)d * HID + lane * 2];
  const float2 b = *(const float2*)&db1[lane * 2];
  const float2 w = *(const float2*)&dw2[lane * 2];
  float h0 = fmaxf(uu.x + vv.x + b.x, 0.0f);
  float h1 = fmaxf(uu.y + vv.y + b.y, 0.0f);
  float sum = h0 * w.x + h1 * w.y;
#pragma unroll
  for (int o = 32; o > 0; o >>= 1) sum += __shfl_down(sum, o);
  if (lane == 0) out[e] = sum + db2[0];
}

extern "C" void kernel_launch(void* const* d_in, const int* in_sizes, int n_in,
                              void* d_out, int out_size, void* d_ws, size_t ws_size,
                              hipStream_t stream) {
  const float* x   = (const float*)d_in[0];
  const int*   ei  = (const int*)d_in[1];
  const int*   eli = (const int*)d_in[2];
  const float* w1l = (const float*)d_in[3];
  const float* b1l = (const float*)d_in[4];
  const float* w1r = (const float*)d_in[5];
  const float* w2l = (const float*)d_in[6];
  const float* b2l = (const float*)d_in[7];
  const float* w2r = (const float*)d_in[8];
  const float* dw1 = (const float*)d_in[9];
  const float* db1 = (const float*)d_in[10];
  const float* dw2 = (const float*)d_in[11];
  const float* db2 = (const float*)d_in[12];
  float* out = (float*)d_out;

  // ---- workspace layout ----
  float* ws     = (float*)d_ws;
  float* inv    = ws;                             // 100000 f
  int*   deg_i  = (int*)(ws + 100000);            // 100000 i
  int*   rowptr = deg_i + 100000;                 // 100008 i
  int*   cursor = rowptr + 100008;                // 100000 i
  int*   csr    = cursor + 100000;                // 1600000 i
  float* cbuf   = (float*)(csr + 1600000);        // N*HID f (mean1/mean2 -> u)
  float* hbuf   = cbuf + (size_t)N_NODES * HID;   // N*HID f (h -> v)

  const int* srcp = ei;
  const int* dstp = ei + N_EDGES;
  const int* lsp  = eli;
  const int* ldp  = eli + N_LBL;

  // ---- CSR build ----
  hipMemsetAsync(deg_i, 0, N_NODES * sizeof(int), stream);
  k_deg<<<N_EDGES / 256, 256, 0, stream>>>(dstp, deg_i);
  k_inv<<<(N_NODES + 255) / 256, 256, 0, stream>>>(deg_i, inv);
  k_scan<<<1, 1024, 0, stream>>>(deg_i, rowptr, cursor);
  k_fill<<<N_EDGES / 256, 256, 0, stream>>>(srcp, dstp, cursor, csr);

  // ---- layer 1: mean1 -> cbuf (64 cols); h = relu(...) -> hbuf ----
  k_agg<64><<<N_NODES / 4, 256, 0, stream>>>(rowptr, csr, x, inv, cbuf);
  k_layer<64, true, false><<<(N_NODES + 63) / 64, 256, 0, stream>>>(
      cbuf, x, w1l, b1l, w1r, nullptr, hbuf, nullptr);

  // ---- layer 2 + decoder-precompute fused:
  //      mean2 -> cbuf; z in LDS; u -> cbuf, v -> hbuf ----
  k_agg<128><<<N_NODES / 4, 256, 0, stream>>>(rowptr, csr, hbuf, inv, cbuf);
  k_layer<128, false, true><<<(N_NODES + 63) / 64, 256, 0, stream>>>(
      cbuf, hbuf, w2l, b2l, w2r, dw1, cbuf, hbuf);

  // ---- decoder edge MLP ----
  k_edge<<<N_LBL / 4, 256, 0, stream>>>(lsp, ldp, cbuf, hbuf, db1, dw2, db2, out);
}